// Round 23
// baseline (125.706 us; speedup 1.0000x reference)
//
#include <hip/hip_runtime.h>
#include <hip/hip_bf16.h>

// MultiHeadSelfAttention: B=2, S=2048, D=1024, H=16, DK=64
// cast_all -> QKV gemm (64x128 tile, 6 blocks/CU) -> transpose V
//          -> flash attention (swapped-QKT, dual-Q, LPT) -> out-proj gemm (64x128)

typedef __attribute__((ext_vector_type(4))) float f32x4;
typedef __attribute__((ext_vector_type(16))) float f32x16;
typedef __attribute__((ext_vector_type(8))) short bf16x8;

#define VSTR 2080  // V^T row stride in elems (2048+32)

#if defined(__has_builtin)
#if __has_builtin(__builtin_amdgcn_permlane32_swap)
#define HAVE_PL32 1
#endif
#endif

__device__ __forceinline__ unsigned short f2bf(float f) {
  unsigned int u = __float_as_uint(f);
  u += 0x7fffu + ((u >> 16) & 1u);
  return (unsigned short)(u >> 16);
}
__device__ __forceinline__ float bf2f(unsigned short s) {
  return __uint_as_float(((unsigned int)s) << 16);
}

__device__ __forceinline__ unsigned int cvtpk_bf16(float lo, float hi) {
  unsigned int r;
  asm("v_cvt_pk_bf16_f32 %0, %1, %2" : "=v"(r) : "v"(lo), "v"(hi));
  return r;
}

// One cast kernel for X + the four weight matrices (fewer launch gaps).
__global__ void cast_all(const float* __restrict__ X, const float* __restrict__ Wq,
                         const float* __restrict__ Wk, const float* __restrict__ Wv,
                         const float* __restrict__ Wo, unsigned short* __restrict__ Xb,
                         unsigned short* __restrict__ Wqkvb, unsigned short* __restrict__ Wob,
                         int nx4, int nw4) {
  int i = blockIdx.x * blockDim.x + threadIdx.x;
  const float* src;
  unsigned short* dst;
  int r;
  if (i < nx4) {
    src = X; dst = Xb; r = i;
  } else {
    int k = i - nx4;
    int sel = k / nw4;
    if (sel >= 4) return;
    r = k - sel * nw4;
    src = (sel == 0) ? Wq : (sel == 1) ? Wk : (sel == 2) ? Wv : Wo;
    dst = (sel < 3) ? (Wqkvb + (size_t)sel * 1024 * 1024) : Wob;
  }
  float4 v = ((const float4*)src)[r];
  ushort4 o = make_ushort4(f2bf(v.x), f2bf(v.y), f2bf(v.z), f2bf(v.w));
  ((ushort4*)dst)[r] = o;
}

typedef __attribute__((address_space(1))) const void gas_t;
typedef __attribute__((address_space(3))) void las_t;

__device__ __forceinline__ void gld_lds16(const unsigned short* g, unsigned short* l) {
  __builtin_amdgcn_global_load_lds((gas_t*)g, (las_t*)l, 16, 0, 0);
}

// Out-projection GEMM: BM=64, BN=128, BK=32 -> 512 blocks = 2 blocks/CU.
__global__ __launch_bounds__(256)
void gemm_bt_f32(const unsigned short* __restrict__ A, const unsigned short* __restrict__ B,
                 float* __restrict__ C, int M, int N, int K) {
  __shared__ unsigned short As[64 * 32];
  __shared__ unsigned short Bs[128 * 32];
  const int tid = threadIdx.x;
  const int lane = tid & 63;
  const int wid = tid >> 6;           // 0..3: column strip of 32
  const int lr = lane & 15, lg = lane >> 4;
  const int m0 = blockIdx.x * 64, n0 = blockIdx.y * 128;

  f32x4 acc[4][2] = {};

  const unsigned short* Ag = A + (size_t)(m0 + (tid >> 2)) * K + (tid & 3) * 8;
  const unsigned short* Bg0 = B + (size_t)(n0 + (tid >> 2)) * K + (tid & 3) * 8;
  const unsigned short* Bg1 = B + (size_t)(n0 + 64 + (tid >> 2)) * K + (tid & 3) * 8;
  unsigned short* Al = &As[tid * 8];
  unsigned short* Bl0 = &Bs[tid * 8];
  unsigned short* Bl1 = &Bs[2048 + tid * 8];

  for (int k0 = 0; k0 < K; k0 += 32) {
    gld_lds16(Ag + k0, Al);
    gld_lds16(Bg0 + k0, Bl0);
    gld_lds16(Bg1 + k0, Bl1);
    asm volatile("s_waitcnt vmcnt(0)" ::: "memory");
    __syncthreads();

    bf16x8 af[4], bfr[2];
#pragma unroll
    for (int i = 0; i < 4; ++i)
      af[i] = *(const bf16x8*)&As[(i * 16 + lr) * 32 + lg * 8];
#pragma unroll
    for (int j = 0; j < 2; ++j)
      bfr[j] = *(const bf16x8*)&Bs[(wid * 32 + j * 16 + lr) * 32 + lg * 8];
#pragma unroll
    for (int i = 0; i < 4; ++i)
#pragma unroll
      for (int j = 0; j < 2; ++j)
        acc[i][j] = __builtin_amdgcn_mfma_f32_16x16x32_bf16(af[i], bfr[j], acc[i][j], 0, 0, 0);
    __syncthreads();
  }

#pragma unroll
  for (int i = 0; i < 4; ++i) {
    const int row = m0 + i * 16 + lg * 4;
#pragma unroll
    for (int j = 0; j < 2; ++j) {
      const int col = n0 + wid * 32 + j * 16 + lr;
#pragma unroll
      for (int r = 0; r < 4; ++r)
        C[(size_t)(row + r) * N + col] = acc[i][j][r];
    }
  }
}

// QKV GEMM: BM=64, BN=128, BK=32 -> grid (64, 24) = 1536 blocks = 6 blocks/CU.
// Epilogue: Q pre-scaled (0.125*log2e), K/V packed per-head.
__global__ __launch_bounds__(256)
void gemm_qkv(const unsigned short* __restrict__ A, const unsigned short* __restrict__ B,
              unsigned short* __restrict__ Qp, unsigned short* __restrict__ Kp,
              unsigned short* __restrict__ Vp) {
  const int K = 1024;
  __shared__ unsigned short As[64 * 32];
  __shared__ unsigned short Bs[128 * 32];
  const int tid = threadIdx.x;
  const int lane = tid & 63;
  const int wid = tid >> 6;           // 0..3: column strip of 32
  const int lr = lane & 15, lg = lane >> 4;
  const int m0 = blockIdx.x * 64, n0 = blockIdx.y * 128;

  f32x4 acc[4][2] = {};

  const unsigned short* Ag = A + (size_t)(m0 + (tid >> 2)) * K + (tid & 3) * 8;
  const unsigned short* Bg0 = B + (size_t)(n0 + (tid >> 2)) * K + (tid & 3) * 8;
  const unsigned short* Bg1 = B + (size_t)(n0 + 64 + (tid >> 2)) * K + (tid & 3) * 8;
  unsigned short* Al = &As[tid * 8];
  unsigned short* Bl0 = &Bs[tid * 8];
  unsigned short* Bl1 = &Bs[2048 + tid * 8];

  for (int k0 = 0; k0 < K; k0 += 32) {
    gld_lds16(Ag + k0, Al);
    gld_lds16(Bg0 + k0, Bl0);
    gld_lds16(Bg1 + k0, Bl1);
    asm volatile("s_waitcnt vmcnt(0)" ::: "memory");
    __syncthreads();

    bf16x8 af[4], bfr[2];
#pragma unroll
    for (int i = 0; i < 4; ++i)
      af[i] = *(const bf16x8*)&As[(i * 16 + lr) * 32 + lg * 8];
#pragma unroll
    for (int j = 0; j < 2; ++j)
      bfr[j] = *(const bf16x8*)&Bs[(wid * 32 + j * 16 + lr) * 32 + lg * 8];
#pragma unroll
    for (int i = 0; i < 4; ++i)
#pragma unroll
      for (int j = 0; j < 2; ++j)
        acc[i][j] = __builtin_amdgcn_mfma_f32_16x16x32_bf16(af[i], bfr[j], acc[i][j], 0, 0, 0);
    __syncthreads();
  }

  const int region = blockIdx.y >> 3;  // 0=Q, 1=K, 2=V (block-uniform)
  const float qs = 0.125f * 1.44269504088896f;
#pragma unroll
  for (int i = 0; i < 4; ++i) {
    const int row0 = m0 + i * 16 + lg * 4;
#pragma unroll
    for (int j = 0; j < 2; ++j) {
      const int col = n0 + wid * 32 + j * 16 + lr;
#pragma unroll
      for (int r = 0; r < 4; ++r) {
        const int row = row0 + r;
        float a = acc[i][j][r];
        const int b = row >> 11, s = row & 2047;
        if (region == 0) {
          Qp[(size_t)row * 1024 + col] = f2bf(a * qs);
        } else {
          const int c = col & 1023, h = c >> 6, d = c & 63;
          unsigned short* dst = (region == 1) ? Kp : Vp;
          dst[(size_t)((b * 16 + h) * 2048 + s) * 64 + d] = f2bf(a);
        }
      }
    }
  }
}

// VTp[bh][d][s] (stride VSTR) = Vp[bh][s][d]. LDS 64x64 double-XOR swizzle.
__global__ __launch_bounds__(256)
void transpose_vp(const unsigned short* __restrict__ Vp, unsigned short* __restrict__ VTp) {
  __shared__ __align__(16) unsigned short t[64 * 64];
  const int tid = threadIdx.x;
  const int bh = blockIdx.y;
  const int s0 = blockIdx.x * 64;
#pragma unroll
  for (int it = 0; it < 2; ++it) {
    int idx = it * 256 + tid;
    int r = idx >> 3, c8 = (idx & 7) * 8;
    bf16x8 v = *(const bf16x8*)(Vp + ((size_t)(bh * 2048 + s0 + r)) * 64 + c8);
    int sw = ((r & 7) ^ ((r >> 3) & 7)) * 8;
    *(bf16x8*)&t[r * 64 + (c8 ^ sw)] = v;
  }
  __syncthreads();
#pragma unroll
  for (int it = 0; it < 2; ++it) {
    int idx = it * 256 + tid;
    int d = idx >> 3, s8 = (idx & 7) * 8;
    unsigned short tmp[8];
#pragma unroll
    for (int j = 0; j < 8; ++j) {
      int row = s8 + j;
      int sw = ((row & 7) ^ ((row >> 3) & 7)) * 8;
      tmp[j] = t[row * 64 + ((d & ~7) ^ sw) + (d & 7)];
    }
    *(bf16x8*)(VTp + (size_t)(bh * 64 + d) * VSTR + s0 + s8) = *(bf16x8*)tmp;
  }
}

// Flash attention, causal, swapped-QKT 32x32, DUAL-Q, no-max softmax, LPT.
// (Identical to R19's attn17 — frozen.)
__global__ __launch_bounds__(256, 2)
void attn17(const unsigned short* __restrict__ Qp, const unsigned short* __restrict__ Kp,
            const unsigned short* __restrict__ VTp, unsigned short* __restrict__ O) {
  const int tid = threadIdx.x;
  const int w = tid >> 6;
  const int lane = tid & 63;
  const int l31 = lane & 31;
  const int hi = lane >> 5;
  const int blk = blockIdx.x;
  const int j = 31 - (blk >> 5);  // LPT: heavy blocks dispatched first
  const int bh = blk & 31;
  const int b = bh >> 4, h = bh & 15;

  __shared__ unsigned short obuf[3][2][32][64];
  __shared__ float ml[4][2][32];

  const unsigned short* Qb = Qp + (size_t)b * 2048 * 1024 + h * 64;
  const unsigned short* Kb = Kp + (size_t)bh * 2048 * 64;
  const unsigned short* Vt = VTp + (size_t)bh * 64 * VSTR;

  const int qt0 = 2 * j, qt1 = 2 * j + 1;
  const int nt = 2 * j + 2;
  const int t0 = (nt * w) >> 2;
  const int t1 = (nt * (w + 1)) >> 2;

  bf16x8 qf0[4], qf1[4];
#pragma unroll
  for (int i = 0; i < 4; ++i) {
    qf0[i] = *(const bf16x8*)(Qb + (size_t)(qt0 * 32 + l31) * 1024 + 16 * i + 8 * hi);
    qf1[i] = *(const bf16x8*)(Qb + (size_t)(qt1 * 32 + l31) * 1024 + 16 * i + 8 * hi);
  }

  f32x16 o00, o01, o10, o11;
#pragma unroll
  for (int r = 0; r < 16; ++r) { o00[r] = 0.f; o01[r] = 0.f; o10[r] = 0.f; o11[r] = 0.f; }
  float Lp0 = 0.f, Lp1 = 0.f;

  for (int t = t0; t < t1; ++t) {
    bf16x8 kf[4];
#pragma unroll
    for (int i = 0; i < 4; ++i)
      kf[i] = *(const bf16x8*)(Kb + (size_t)(t * 32 + l31) * 64 + 16 * i + 8 * hi);
    bf16x8 vf[2][2];
#pragma unroll
    for (int c = 0; c < 2; ++c)
#pragma unroll
      for (int dh = 0; dh < 2; ++dh)
        vf[c][dh] = *(const bf16x8*)(Vt + (size_t)(dh * 32 + l31) * VSTR + t * 32 + c * 16 + 8 * hi);

    f32x16 st0, st1;
#pragma unroll
    for (int r = 0; r < 16; ++r) { st0[r] = 0.f; st1[r] = 0.f; }
    __builtin_amdgcn_s_setprio(1);
#pragma unroll
    for (int i = 0; i < 4; ++i) {
      st0 = __builtin_amdgcn_mfma_f32_32x32x16_bf16(kf[i], qf0[i], st0, 0, 0, 0);
      st1 = __builtin_amdgcn_mfma_f32_32x32x16_bf16(kf[i], qf1[i], st1, 0, 0, 0);
    }
    __builtin_amdgcn_s_setprio(0);

    {
      const int dd0 = (t - qt0) * 32;
      const int dd1 = (t - qt1) * 32;
      if (dd0 >= 0) {
#pragma unroll
        for (int r = 0; r < 16; ++r) {
          int kvi = (r & 3) + 8 * (r >> 2) + 4 * hi;
          if (kvi + dd0 > l31) st0[r] = -3.0e38f;
        }
      }
      if (dd1 >= 0) {
#pragma unroll
        for (int r = 0; r < 16; ++r) {
          int kvi = (r & 3) + 8 * (r >> 2) + 4 * hi;
          if (kvi + dd1 > l31) st1[r] = -3.0e38f;
        }
      }
    }

    float p0[16], p1[16];
    float rs0 = 0.f, rs1 = 0.f;
#pragma unroll
    for (int r = 0; r < 16; ++r) {
      p0[r] = exp2f(st0[r]);
      p1[r] = exp2f(st1[r]);
      rs0 += p0[r];
      rs1 += p1[r];
    }
    Lp0 += rs0;
    Lp1 += rs1;

    unsigned int pw0[8], pw1[8];
#pragma unroll
    for (int g = 0; g < 4; ++g) {
      pw0[2 * g]     = cvtpk_bf16(p0[4 * g],     p0[4 * g + 1]);
      pw0[2 * g + 1] = cvtpk_bf16(p0[4 * g + 2], p0[4 * g + 3]);
      pw1[2 * g]     = cvtpk_bf16(p1[4 * g],     p1[4 * g + 1]);
      pw1[2 * g + 1] = cvtpk_bf16(p1[4 * g + 2], p1[4 * g + 3]);
    }
#pragma unroll
    for (int c = 0; c < 2; ++c) {
      unsigned int a00 = pw0[4 * c], a01 = pw0[4 * c + 1];
      unsigned int b00 = pw0[4 * c + 2], b01 = pw0[4 * c + 3];
      unsigned int a10 = pw1[4 * c], a11 = pw1[4 * c + 1];
      unsigned int b10 = pw1[4 * c + 2], b11 = pw1[4 * c + 3];
      union { unsigned int u[4]; bf16x8 v; } af0, af1;
#ifdef HAVE_PL32
      auto r00 = __builtin_amdgcn_permlane32_swap(a00, b00, false, false);
      auto r01 = __builtin_amdgcn_permlane32_swap(a01, b01, false, false);
      auto r10 = __builtin_amdgcn_permlane32_swap(a10, b10, false, false);
      auto r11 = __builtin_amdgcn_permlane32_swap(a11, b11, false, false);
      af0.u[0] = r00[0]; af0.u[2] = r00[1];
      af0.u[1] = r01[0]; af0.u[3] = r01[1];
      af1.u[0] = r10[0]; af1.u[2] = r10[1];
      af1.u[1] = r11[0]; af1.u[3] = r11[1];
#else
      unsigned int s00 = __shfl_xor(a00, 32), s01 = __shfl_xor(a01, 32);
      unsigned int t00 = __shfl_xor(b00, 32), t01 = __shfl_xor(b01, 32);
      unsigned int s10 = __shfl_xor(a10, 32), s11 = __shfl_xor(a11, 32);
      unsigned int t10 = __shfl_xor(b10, 32), t11 = __shfl_xor(b11, 32);
      af0.u[0] = hi ? t00 : a00;
      af0.u[1] = hi ? t01 : a01;
      af0.u[2] = hi ? b00 : s00;
      af0.u[3] = hi ? b01 : s01;
      af1.u[0] = hi ? t10 : a10;
      af1.u[1] = hi ? t11 : a11;
      af1.u[2] = hi ? b10 : s10;
      af1.u[3] = hi ? b11 : s11;
#endif
      __builtin_amdgcn_s_setprio(1);
      o00 = __builtin_amdgcn_mfma_f32_32x32x16_bf16(af0.v, vf[c][0], o00, 0, 0, 0);
      o01 = __builtin_amdgcn_mfma_f32_32x32x16_bf16(af0.v, vf[c][1], o01, 0, 0, 0);
      o10 = __builtin_amdgcn_mfma_f32_32x32x16_bf16(af1.v, vf[c][0], o10, 0, 0, 0);
      o11 = __builtin_amdgcn_mfma_f32_32x32x16_bf16(af1.v, vf[c][1], o11, 0, 0, 0);
      __builtin_amdgcn_s_setprio(0);
    }
  }

  float Lt0 = Lp0 + __shfl_xor(Lp0, 32);
  float Lt1 = Lp1 + __shfl_xor(Lp1, 32);
  if (!hi) { ml[w][0][l31] = Lt0; ml[w][1][l31] = Lt1; }
  if (w != 0) {
#pragma unroll
    for (int r = 0; r < 16; ++r) {
      int qr = (r & 3) + 8 * (r >> 2) + 4 * hi;
      obuf[w - 1][0][qr][l31]      = f2bf(o00[r]);
      obuf[w - 1][0][qr][32 + l31] = f2bf(o01[r]);
      obuf[w - 1][1][qr][l31]      = f2bf(o10[r]);
      obuf[w - 1][1][qr][32 + l31] = f2bf(o11[r]);
    }
  }
  __syncthreads();
  if (w == 0) {
#pragma unroll
    for (int r = 0; r < 16; ++r) {
      int qr = (r & 3) + 8 * (r >> 2) + 4 * hi;
      float L0 = ml[0][0][qr] + ml[1][0][qr] + ml[2][0][qr] + ml[3][0][qr];
      float L1 = ml[0][1][qr] + ml[1][1][qr] + ml[2][1][qr] + ml[3][1][qr];
      float i0 = 1.0f / L0, i1 = 1.0f / L1;
      float v00 = o00[r] + bf2f(obuf[0][0][qr][l31])      + bf2f(obuf[1][0][qr][l31])      + bf2f(obuf[2][0][qr][l31]);
      float v01 = o01[r] + bf2f(obuf[0][0][qr][32 + l31]) + bf2f(obuf[1][0][qr][32 + l31]) + bf2f(obuf[2][0][qr][32 + l31]);
      float v10 = o10[r] + bf2f(obuf[0][1][qr][l31])      + bf2f(obuf[1][1][qr][l31])      + bf2f(obuf[2][1][qr][l31]);
      float v11 = o11[r] + bf2f(obuf[0][1][qr][32 + l31]) + bf2f(obuf[1][1][qr][32 + l31]) + bf2f(obuf[2][1][qr][32 + l31]);
      size_t base0 = (size_t)(b * 2048 + qt0 * 32 + qr) * 1024 + h * 64;
      size_t base1 = (size_t)(b * 2048 + qt1 * 32 + qr) * 1024 + h * 64;
      O[base0 + l31]      = f2bf(v00 * i0);
      O[base0 + 32 + l31] = f2bf(v01 * i0);
      O[base1 + l31]      = f2bf(v10 * i1);
      O[base1 + 32 + l31] = f2bf(v11 * i1);
    }
  }
}

extern "C" void kernel_launch(void* const* d_in, const int* in_sizes, int n_in,
                              void* d_out, int out_size, void* d_ws, size_t ws_size,
                              hipStream_t stream) {
  const float* X  = (const float*)d_in[0];
  const float* Wq = (const float*)d_in[1];
  const float* Wk = (const float*)d_in[2];
  const float* Wv = (const float*)d_in[3];
  const float* Wo = (const float*)d_in[4];
  float* out = (float*)d_out;

  char* ws = (char*)d_ws;
  unsigned short* Xb    = (unsigned short*)(ws);                            // 8 MB (dead after gemm_qkv)
  unsigned short* Ob    = (unsigned short*)(ws);                            // 8 MB (reuses Xb region)
  unsigned short* Wqkvb = (unsigned short*)(ws + (size_t)8  * 1024 * 1024); // 6 MB
  unsigned short* Wob   = (unsigned short*)(ws + (size_t)14 * 1024 * 1024); // 2 MB
  unsigned short* Qp    = (unsigned short*)(ws + (size_t)16 * 1024 * 1024); // 8 MB
  unsigned short* Kp    = (unsigned short*)(ws + (size_t)24 * 1024 * 1024); // 8 MB
  unsigned short* Vp    = (unsigned short*)(ws + (size_t)32 * 1024 * 1024); // 8 MB
  unsigned short* VTp   = (unsigned short*)(ws + (size_t)40 * 1024 * 1024); // 8.5 MB

  const int NX4 = (2 * 2048 * 1024) / 4;  // 1048576
  const int NW4 = (1024 * 1024) / 4;      // 262144
  const int NTOT = NX4 + 4 * NW4;         // 2097152
  cast_all<<<dim3((NTOT + 255) / 256), dim3(256), 0, stream>>>(X, Wq, Wk, Wv, Wo, Xb, Wqkvb, Wob, NX4, NW4);

  gemm_qkv<<<dim3(64, 24), dim3(256), 0, stream>>>(Xb, Wqkvb, Qp, Kp, Vp);
  transpose_vp<<<dim3(32, 32), dim3(256), 0, stream>>>(Vp, VTp);
  attn17<<<dim3(1024), dim3(256), 0, stream>>>(Qp, Kp, VTp, Ob);
  gemm_bt_f32<<<dim3(64, 8), dim3(256), 0, stream>>>(Ob, Wob, out, 4096, 1024, 1024);
}

// Round 24
// 111.248 us; speedup vs baseline: 1.1300x; 1.1300x over previous
//
#include <hip/hip_runtime.h>
#include <hip/hip_bf16.h>

// MultiHeadSelfAttention: B=2, S=2048, D=1024, H=16, DK=64
// cast_all -> QKV gemm (128x128 m97, 3 blocks/CU) -> transpose V
//          -> flash attention (swapped-QKT, dual-Q, LPT) -> out-proj gemm (64x128, 2 blocks/CU)

typedef __attribute__((ext_vector_type(4))) float f32x4;
typedef __attribute__((ext_vector_type(16))) float f32x16;
typedef __attribute__((ext_vector_type(8))) short bf16x8;

#define VSTR 2080  // V^T row stride in elems (2048+32)

#if defined(__has_builtin)
#if __has_builtin(__builtin_amdgcn_permlane32_swap)
#define HAVE_PL32 1
#endif
#endif

__device__ __forceinline__ unsigned short f2bf(float f) {
  unsigned int u = __float_as_uint(f);
  u += 0x7fffu + ((u >> 16) & 1u);
  return (unsigned short)(u >> 16);
}
__device__ __forceinline__ float bf2f(unsigned short s) {
  return __uint_as_float(((unsigned int)s) << 16);
}

__device__ __forceinline__ unsigned int cvtpk_bf16(float lo, float hi) {
  unsigned int r;
  asm("v_cvt_pk_bf16_f32 %0, %1, %2" : "=v"(r) : "v"(lo), "v"(hi));
  return r;
}

// One cast kernel for X + the four weight matrices.
__global__ void cast_all(const float* __restrict__ X, const float* __restrict__ Wq,
                         const float* __restrict__ Wk, const float* __restrict__ Wv,
                         const float* __restrict__ Wo, unsigned short* __restrict__ Xb,
                         unsigned short* __restrict__ Wqkvb, unsigned short* __restrict__ Wob,
                         int nx4, int nw4) {
  int i = blockIdx.x * blockDim.x + threadIdx.x;
  const float* src;
  unsigned short* dst;
  int r;
  if (i < nx4) {
    src = X; dst = Xb; r = i;
  } else {
    int k = i - nx4;
    int sel = k / nw4;
    if (sel >= 4) return;
    r = k - sel * nw4;
    src = (sel == 0) ? Wq : (sel == 1) ? Wk : (sel == 2) ? Wv : Wo;
    dst = (sel < 3) ? (Wqkvb + (size_t)sel * 1024 * 1024) : Wob;
  }
  float4 v = ((const float4*)src)[r];
  ushort4 o = make_ushort4(f2bf(v.x), f2bf(v.y), f2bf(v.z), f2bf(v.w));
  ((ushort4*)dst)[r] = o;
}

typedef __attribute__((address_space(1))) const void gas_t;
typedef __attribute__((address_space(3))) void las_t;

__device__ __forceinline__ void gld_lds16(const unsigned short* g, unsigned short* l) {
  __builtin_amdgcn_global_load_lds((gas_t*)g, (las_t*)l, 16, 0, 0);
}

// Out-projection GEMM: BM=64, BN=128, BK=32 -> 512 blocks = 2 blocks/CU (R22-proven).
__global__ __launch_bounds__(256)
void gemm_bt_f32(const unsigned short* __restrict__ A, const unsigned short* __restrict__ B,
                 float* __restrict__ C, int M, int N, int K) {
  __shared__ unsigned short As[64 * 32];
  __shared__ unsigned short Bs[128 * 32];
  const int tid = threadIdx.x;
  const int lane = tid & 63;
  const int wid = tid >> 6;           // 0..3: column strip of 32
  const int lr = lane & 15, lg = lane >> 4;
  const int m0 = blockIdx.x * 64, n0 = blockIdx.y * 128;

  f32x4 acc[4][2] = {};

  const unsigned short* Ag = A + (size_t)(m0 + (tid >> 2)) * K + (tid & 3) * 8;
  const unsigned short* Bg0 = B + (size_t)(n0 + (tid >> 2)) * K + (tid & 3) * 8;
  const unsigned short* Bg1 = B + (size_t)(n0 + 64 + (tid >> 2)) * K + (tid & 3) * 8;
  unsigned short* Al = &As[tid * 8];
  unsigned short* Bl0 = &Bs[tid * 8];
  unsigned short* Bl1 = &Bs[2048 + tid * 8];

  for (int k0 = 0; k0 < K; k0 += 32) {
    gld_lds16(Ag + k0, Al);
    gld_lds16(Bg0 + k0, Bl0);
    gld_lds16(Bg1 + k0, Bl1);
    asm volatile("s_waitcnt vmcnt(0)" ::: "memory");
    __syncthreads();

    bf16x8 af[4], bfr[2];
#pragma unroll
    for (int i = 0; i < 4; ++i)
      af[i] = *(const bf16x8*)&As[(i * 16 + lr) * 32 + lg * 8];
#pragma unroll
    for (int j = 0; j < 2; ++j)
      bfr[j] = *(const bf16x8*)&Bs[(wid * 32 + j * 16 + lr) * 32 + lg * 8];
#pragma unroll
    for (int i = 0; i < 4; ++i)
#pragma unroll
      for (int j = 0; j < 2; ++j)
        acc[i][j] = __builtin_amdgcn_mfma_f32_16x16x32_bf16(af[i], bfr[j], acc[i][j], 0, 0, 0);
    __syncthreads();
  }

#pragma unroll
  for (int i = 0; i < 4; ++i) {
    const int row = m0 + i * 16 + lg * 4;
#pragma unroll
    for (int j = 0; j < 2; ++j) {
      const int col = n0 + wid * 32 + j * 16 + lr;
#pragma unroll
      for (int r = 0; r < 4; ++r)
        C[(size_t)(row + r) * N + col] = acc[i][j][r];
    }
  }
}

// QKV GEMM: 128x128 m97 body (R22-proven, 768 blocks = 3 blocks/CU).
// Epilogue: Q pre-scaled (0.125*log2e), K/V packed per-head.
__global__ __launch_bounds__(256)
void gemm_qkv(const unsigned short* __restrict__ A, const unsigned short* __restrict__ B,
              unsigned short* __restrict__ Qp, unsigned short* __restrict__ Kp,
              unsigned short* __restrict__ Vp) {
  const int K = 1024;
  __shared__ unsigned short As[128 * 32];
  __shared__ unsigned short Bs[128 * 32];
  const int tid = threadIdx.x;
  const int lane = tid & 63;
  const int wid = tid >> 6;
  const int wr = wid >> 1, wc = wid & 1;
  const int lr = lane & 15, lg = lane >> 4;
  const int m0 = blockIdx.x * 128, n0 = blockIdx.y * 128;

  f32x4 acc[4][4] = {};

  const int srow = tid >> 2;
  const int scol = (tid & 3) * 8;
  const unsigned short* Ag = A + (size_t)(m0 + srow) * K + scol;
  const unsigned short* Bg = B + (size_t)(n0 + srow) * K + scol;
  unsigned short* Al = &As[tid * 8];
  unsigned short* Bl = &Bs[tid * 8];

  for (int k0 = 0; k0 < K; k0 += 32) {
    gld_lds16(Ag + k0, Al);
    gld_lds16(Ag + k0 + (size_t)64 * K, Al + 2048);
    gld_lds16(Bg + k0, Bl);
    gld_lds16(Bg + k0 + (size_t)64 * K, Bl + 2048);
    asm volatile("s_waitcnt vmcnt(0)" ::: "memory");
    __syncthreads();

    bf16x8 af[4], bfr[4];
#pragma unroll
    for (int i = 0; i < 4; ++i)
      af[i] = *(const bf16x8*)&As[(wr * 64 + i * 16 + lr) * 32 + lg * 8];
#pragma unroll
    for (int j = 0; j < 4; ++j)
      bfr[j] = *(const bf16x8*)&Bs[(wc * 64 + j * 16 + lr) * 32 + lg * 8];
#pragma unroll
    for (int i = 0; i < 4; ++i)
#pragma unroll
      for (int j = 0; j < 4; ++j)
        acc[i][j] = __builtin_amdgcn_mfma_f32_16x16x32_bf16(af[i], bfr[j], acc[i][j], 0, 0, 0);
    __syncthreads();
  }

  const int region = blockIdx.y >> 3;  // 0=Q, 1=K, 2=V (block-uniform)
  const float qs = 0.125f * 1.44269504088896f;
#pragma unroll
  for (int i = 0; i < 4; ++i) {
    const int row0 = m0 + wr * 64 + i * 16 + lg * 4;
#pragma unroll
    for (int j = 0; j < 4; ++j) {
      const int col = n0 + wc * 64 + j * 16 + lr;
#pragma unroll
      for (int r = 0; r < 4; ++r) {
        const int row = row0 + r;
        float a = acc[i][j][r];
        const int b = row >> 11, s = row & 2047;
        if (region == 0) {
          Qp[(size_t)row * 1024 + col] = f2bf(a * qs);
        } else {
          const int c = col & 1023, h = c >> 6, d = c & 63;
          unsigned short* dst = (region == 1) ? Kp : Vp;
          dst[(size_t)((b * 16 + h) * 2048 + s) * 64 + d] = f2bf(a);
        }
      }
    }
  }
}

// VTp[bh][d][s] (stride VSTR) = Vp[bh][s][d]. LDS 64x64 double-XOR swizzle.
__global__ __launch_bounds__(256)
void transpose_vp(const unsigned short* __restrict__ Vp, unsigned short* __restrict__ VTp) {
  __shared__ __align__(16) unsigned short t[64 * 64];
  const int tid = threadIdx.x;
  const int bh = blockIdx.y;
  const int s0 = blockIdx.x * 64;
#pragma unroll
  for (int it = 0; it < 2; ++it) {
    int idx = it * 256 + tid;
    int r = idx >> 3, c8 = (idx & 7) * 8;
    bf16x8 v = *(const bf16x8*)(Vp + ((size_t)(bh * 2048 + s0 + r)) * 64 + c8);
    int sw = ((r & 7) ^ ((r >> 3) & 7)) * 8;
    *(bf16x8*)&t[r * 64 + (c8 ^ sw)] = v;
  }
  __syncthreads();
#pragma unroll
  for (int it = 0; it < 2; ++it) {
    int idx = it * 256 + tid;
    int d = idx >> 3, s8 = (idx & 7) * 8;
    unsigned short tmp[8];
#pragma unroll
    for (int j = 0; j < 8; ++j) {
      int row = s8 + j;
      int sw = ((row & 7) ^ ((row >> 3) & 7)) * 8;
      tmp[j] = t[row * 64 + ((d & ~7) ^ sw) + (d & 7)];
    }
    *(bf16x8*)(VTp + (size_t)(bh * 64 + d) * VSTR + s0 + s8) = *(bf16x8*)tmp;
  }
}

// Flash attention, causal, swapped-QKT 32x32, DUAL-Q, no-max softmax, LPT.
// (Identical to R19's attn17 — frozen.)
__global__ __launch_bounds__(256, 2)
void attn17(const unsigned short* __restrict__ Qp, const unsigned short* __restrict__ Kp,
            const unsigned short* __restrict__ VTp, unsigned short* __restrict__ O) {
  const int tid = threadIdx.x;
  const int w = tid >> 6;
  const int lane = tid & 63;
  const int l31 = lane & 31;
  const int hi = lane >> 5;
  const int blk = blockIdx.x;
  const int j = 31 - (blk >> 5);  // LPT: heavy blocks dispatched first
  const int bh = blk & 31;
  const int b = bh >> 4, h = bh & 15;

  __shared__ unsigned short obuf[3][2][32][64];
  __shared__ float ml[4][2][32];

  const unsigned short* Qb = Qp + (size_t)b * 2048 * 1024 + h * 64;
  const unsigned short* Kb = Kp + (size_t)bh * 2048 * 64;
  const unsigned short* Vt = VTp + (size_t)bh * 64 * VSTR;

  const int qt0 = 2 * j, qt1 = 2 * j + 1;
  const int nt = 2 * j + 2;
  const int t0 = (nt * w) >> 2;
  const int t1 = (nt * (w + 1)) >> 2;

  bf16x8 qf0[4], qf1[4];
#pragma unroll
  for (int i = 0; i < 4; ++i) {
    qf0[i] = *(const bf16x8*)(Qb + (size_t)(qt0 * 32 + l31) * 1024 + 16 * i + 8 * hi);
    qf1[i] = *(const bf16x8*)(Qb + (size_t)(qt1 * 32 + l31) * 1024 + 16 * i + 8 * hi);
  }

  f32x16 o00, o01, o10, o11;
#pragma unroll
  for (int r = 0; r < 16; ++r) { o00[r] = 0.f; o01[r] = 0.f; o10[r] = 0.f; o11[r] = 0.f; }
  float Lp0 = 0.f, Lp1 = 0.f;

  for (int t = t0; t < t1; ++t) {
    bf16x8 kf[4];
#pragma unroll
    for (int i = 0; i < 4; ++i)
      kf[i] = *(const bf16x8*)(Kb + (size_t)(t * 32 + l31) * 64 + 16 * i + 8 * hi);
    bf16x8 vf[2][2];
#pragma unroll
    for (int c = 0; c < 2; ++c)
#pragma unroll
      for (int dh = 0; dh < 2; ++dh)
        vf[c][dh] = *(const bf16x8*)(Vt + (size_t)(dh * 32 + l31) * VSTR + t * 32 + c * 16 + 8 * hi);

    f32x16 st0, st1;
#pragma unroll
    for (int r = 0; r < 16; ++r) { st0[r] = 0.f; st1[r] = 0.f; }
    __builtin_amdgcn_s_setprio(1);
#pragma unroll
    for (int i = 0; i < 4; ++i) {
      st0 = __builtin_amdgcn_mfma_f32_32x32x16_bf16(kf[i], qf0[i], st0, 0, 0, 0);
      st1 = __builtin_amdgcn_mfma_f32_32x32x16_bf16(kf[i], qf1[i], st1, 0, 0, 0);
    }
    __builtin_amdgcn_s_setprio(0);

    {
      const int dd0 = (t - qt0) * 32;
      const int dd1 = (t - qt1) * 32;
      if (dd0 >= 0) {
#pragma unroll
        for (int r = 0; r < 16; ++r) {
          int kvi = (r & 3) + 8 * (r >> 2) + 4 * hi;
          if (kvi + dd0 > l31) st0[r] = -3.0e38f;
        }
      }
      if (dd1 >= 0) {
#pragma unroll
        for (int r = 0; r < 16; ++r) {
          int kvi = (r & 3) + 8 * (r >> 2) + 4 * hi;
          if (kvi + dd1 > l31) st1[r] = -3.0e38f;
        }
      }
    }

    float p0[16], p1[16];
    float rs0 = 0.f, rs1 = 0.f;
#pragma unroll
    for (int r = 0; r < 16; ++r) {
      p0[r] = exp2f(st0[r]);
      p1[r] = exp2f(st1[r]);
      rs0 += p0[r];
      rs1 += p1[r];
    }
    Lp0 += rs0;
    Lp1 += rs1;

    unsigned int pw0[8], pw1[8];
#pragma unroll
    for (int g = 0; g < 4; ++g) {
      pw0[2 * g]     = cvtpk_bf16(p0[4 * g],     p0[4 * g + 1]);
      pw0[2 * g + 1] = cvtpk_bf16(p0[4 * g + 2], p0[4 * g + 3]);
      pw1[2 * g]     = cvtpk_bf16(p1[4 * g],     p1[4 * g + 1]);
      pw1[2 * g + 1] = cvtpk_bf16(p1[4 * g + 2], p1[4 * g + 3]);
    }
#pragma unroll
    for (int c = 0; c < 2; ++c) {
      unsigned int a00 = pw0[4 * c], a01 = pw0[4 * c + 1];
      unsigned int b00 = pw0[4 * c + 2], b01 = pw0[4 * c + 3];
      unsigned int a10 = pw1[4 * c], a11 = pw1[4 * c + 1];
      unsigned int b10 = pw1[4 * c + 2], b11 = pw1[4 * c + 3];
      union { unsigned int u[4]; bf16x8 v; } af0, af1;
#ifdef HAVE_PL32
      auto r00 = __builtin_amdgcn_permlane32_swap(a00, b00, false, false);
      auto r01 = __builtin_amdgcn_permlane32_swap(a01, b01, false, false);
      auto r10 = __builtin_amdgcn_permlane32_swap(a10, b10, false, false);
      auto r11 = __builtin_amdgcn_permlane32_swap(a11, b11, false, false);
      af0.u[0] = r00[0]; af0.u[2] = r00[1];
      af0.u[1] = r01[0]; af0.u[3] = r01[1];
      af1.u[0] = r10[0]; af1.u[2] = r10[1];
      af1.u[1] = r11[0]; af1.u[3] = r11[1];
#else
      unsigned int s00 = __shfl_xor(a00, 32), s01 = __shfl_xor(a01, 32);
      unsigned int t00 = __shfl_xor(b00, 32), t01 = __shfl_xor(b01, 32);
      unsigned int s10 = __shfl_xor(a10, 32), s11 = __shfl_xor(a11, 32);
      unsigned int t10 = __shfl_xor(b10, 32), t11 = __shfl_xor(b11, 32);
      af0.u[0] = hi ? t00 : a00;
      af0.u[1] = hi ? t01 : a01;
      af0.u[2] = hi ? b00 : s00;
      af0.u[3] = hi ? b01 : s01;
      af1.u[0] = hi ? t10 : a10;
      af1.u[1] = hi ? t11 : a11;
      af1.u[2] = hi ? b10 : s10;
      af1.u[3] = hi ? b11 : s11;
#endif
      __builtin_amdgcn_s_setprio(1);
      o00 = __builtin_amdgcn_mfma_f32_32x32x16_bf16(af0.v, vf[c][0], o00, 0, 0, 0);
      o01 = __builtin_amdgcn_mfma_f32_32x32x16_bf16(af0.v, vf[c][1], o01, 0, 0, 0);
      o10 = __builtin_amdgcn_mfma_f32_32x32x16_bf16(af1.v, vf[c][0], o10, 0, 0, 0);
      o11 = __builtin_amdgcn_mfma_f32_32x32x16_bf16(af1.v, vf[c][1], o11, 0, 0, 0);
      __builtin_amdgcn_s_setprio(0);
    }
  }

  float Lt0 = Lp0 + __shfl_xor(Lp0, 32);
  float Lt1 = Lp1 + __shfl_xor(Lp1, 32);
  if (!hi) { ml[w][0][l31] = Lt0; ml[w][1][l31] = Lt1; }
  if (w != 0) {
#pragma unroll
    for (int r = 0; r < 16; ++r) {
      int qr = (r & 3) + 8 * (r >> 2) + 4 * hi;
      obuf[w - 1][0][qr][l31]      = f2bf(o00[r]);
      obuf[w - 1][0][qr][32 + l31] = f2bf(o01[r]);
      obuf[w - 1][1][qr][l31]      = f2bf(o10[r]);
      obuf[w - 1][1][qr][32 + l31] = f2bf(o11[r]);
    }
  }
  __syncthreads();
  if (w == 0) {
#pragma unroll
    for (int r = 0; r < 16; ++r) {
      int qr = (r & 3) + 8 * (r >> 2) + 4 * hi;
      float L0 = ml[0][0][qr] + ml[1][0][qr] + ml[2][0][qr] + ml[3][0][qr];
      float L1 = ml[0][1][qr] + ml[1][1][qr] + ml[2][1][qr] + ml[3][1][qr];
      float i0 = 1.0f / L0, i1 = 1.0f / L1;
      float v00 = o00[r] + bf2f(obuf[0][0][qr][l31])      + bf2f(obuf[1][0][qr][l31])      + bf2f(obuf[2][0][qr][l31]);
      float v01 = o01[r] + bf2f(obuf[0][0][qr][32 + l31]) + bf2f(obuf[1][0][qr][32 + l31]) + bf2f(obuf[2][0][qr][32 + l31]);
      float v10 = o10[r] + bf2f(obuf[0][1][qr][l31])      + bf2f(obuf[1][1][qr][l31])      + bf2f(obuf[2][1][qr][l31]);
      float v11 = o11[r] + bf2f(obuf[0][1][qr][32 + l31]) + bf2f(obuf[1][1][qr][32 + l31]) + bf2f(obuf[2][1][qr][32 + l31]);
      size_t base0 = (size_t)(b * 2048 + qt0 * 32 + qr) * 1024 + h * 64;
      size_t base1 = (size_t)(b * 2048 + qt1 * 32 + qr) * 1024 + h * 64;
      O[base0 + l31]      = f2bf(v00 * i0);
      O[base0 + 32 + l31] = f2bf(v01 * i0);
      O[base1 + l31]      = f2bf(v10 * i1);
      O[base1 + 32 + l31] = f2bf(v11 * i1);
    }
  }
}

extern "C" void kernel_launch(void* const* d_in, const int* in_sizes, int n_in,
                              void* d_out, int out_size, void* d_ws, size_t ws_size,
                              hipStream_t stream) {
  const float* X  = (const float*)d_in[0];
  const float* Wq = (const float*)d_in[1];
  const float* Wk = (const float*)d_in[2];
  const float* Wv = (const float*)d_in[3];
  const float* Wo = (const float*)d_in[4];
  float* out = (float*)d_out;

  char* ws = (char*)d_ws;
  unsigned short* Xb    = (unsigned short*)(ws);                            // 8 MB (dead after gemm_qkv)
  unsigned short* Ob    = (unsigned short*)(ws);                            // 8 MB (reuses Xb region)
  unsigned short* Wqkvb = (unsigned short*)(ws + (size_t)8  * 1024 * 1024); // 6 MB
  unsigned short* Wob   = (unsigned short*)(ws + (size_t)14 * 1024 * 1024); // 2 MB
  unsigned short* Qp    = (unsigned short*)(ws + (size_t)16 * 1024 * 1024); // 8 MB
  unsigned short* Kp    = (unsigned short*)(ws + (size_t)24 * 1024 * 1024); // 8 MB
  unsigned short* Vp    = (unsigned short*)(ws + (size_t)32 * 1024 * 1024); // 8 MB
  unsigned short* VTp   = (unsigned short*)(ws + (size_t)40 * 1024 * 1024); // 8.5 MB

  const int NX4 = (2 * 2048 * 1024) / 4;  // 1048576
  const int NW4 = (1024 * 1024) / 4;      // 262144
  const int NTOT = NX4 + 4 * NW4;         // 2097152
  cast_all<<<dim3((NTOT + 255) / 256), dim3(256), 0, stream>>>(X, Wq, Wk, Wv, Wo, Xb, Wqkvb, Wob, NX4, NW4);

  gemm_qkv<<<dim3(32, 24), dim3(256), 0, stream>>>(Xb, Wqkvb, Qp, Kp, Vp);
  transpose_vp<<<dim3(32, 32), dim3(256), 0, stream>>>(Vp, VTp);
  attn17<<<dim3(1024), dim3(256), 0, stream>>>(Qp, Kp, VTp, Ob);
  gemm_bt_f32<<<dim3(64, 8), dim3(256), 0, stream>>>(Ob, Wob, out, 4096, 1024, 1024);
}